// Round 1
// baseline (250.393 us; speedup 1.0000x reference)
//
#include <hip/hip_runtime.h>
#include <stdint.h>

#define N_Q 16384
#define M_P 1024
#define D_K 1024

typedef __attribute__((ext_vector_type(8))) __bf16 bf16x8;
typedef __attribute__((ext_vector_type(4))) float floatx4;
typedef __attribute__((ext_vector_type(4))) unsigned int uint4v;

#define AS1 __attribute__((address_space(1)))
#define AS3 __attribute__((address_space(3)))

__device__ __forceinline__ unsigned short f2bf(float f) {
    unsigned int u = __float_as_uint(f);
    u += 0x7fffu + ((u >> 16) & 1u);   // round-to-nearest-even
    return (unsigned short)(u >> 16);
}
__device__ __forceinline__ float bf2f(unsigned short h) {
    return __uint_as_float(((unsigned int)h) << 16);
}

// Split 8 fp32 (one k-chunk) -> packed bf16 hi (16B) + lo (16B).
// v_perm packs two hi-halves per instruction; trunc-hi + residual-lo
// (total rel err ~2^-16 per element -> logit err ~1e-3).
__device__ __forceinline__ void split_chunk(floatx4 f0, floatx4 f1,
                                            uint4v* hi, uint4v* lo) {
    float e[8] = {f0.x, f0.y, f0.z, f0.w, f1.x, f1.y, f1.z, f1.w};
    unsigned int hb[4], lb[4];
#pragma unroll
    for (int p = 0; p < 4; ++p) {
        unsigned int u0 = __float_as_uint(e[2 * p]);
        unsigned int u1 = __float_as_uint(e[2 * p + 1]);
        hb[p] = __builtin_amdgcn_perm(u1, u0, 0x07060302);  // [u0>>16, u1>>16]
        float l0 = e[2 * p]     - __uint_as_float(u0 & 0xffff0000u);
        float l1 = e[2 * p + 1] - __uint_as_float(u1 & 0xffff0000u);
        lb[p] = __builtin_amdgcn_perm(__float_as_uint(l1), __float_as_uint(l0),
                                      0x07060302);
    }
    uint4v h = {hb[0], hb[1], hb[2], hb[3]};
    uint4v l = {lb[0], lb[1], lb[2], lb[3]};
    *hi = h;
    *lo = l;
}

// ---------------------------------------------------------------------------
// Proto convert: split fp32 -> bf16 hi/lo + p2[m]. One block per row. ~5 us.
// ---------------------------------------------------------------------------
__global__ __launch_bounds__(256) void convert_proto_kernel(
    const float* __restrict__ proto, unsigned short* __restrict__ ph,
    unsigned short* __restrict__ pl, float* __restrict__ p2) {
    __shared__ float sred[4];
    int m = blockIdx.x;
    int t = threadIdx.x;
    size_t base4 = (size_t)m * (D_K / 4) + t;
    float4 v = ((const float4*)proto)[base4];
    ushort4 h, l;
    h.x = f2bf(v.x); l.x = f2bf(v.x - bf2f(h.x));
    h.y = f2bf(v.y); l.y = f2bf(v.y - bf2f(h.y));
    h.z = f2bf(v.z); l.z = f2bf(v.z - bf2f(h.z));
    h.w = f2bf(v.w); l.w = f2bf(v.w - bf2f(h.w));
    ((ushort4*)ph)[base4] = h;
    ((ushort4*)pl)[base4] = l;
    float sq = v.x * v.x + v.y * v.y + v.z * v.z + v.w * v.w;
#pragma unroll
    for (int off = 1; off < 64; off <<= 1) sq += __shfl_xor(sq, off);
    if ((t & 63) == 0) sred[t >> 6] = sq;
    __syncthreads();
    if (t == 0) p2[m] = sred[0] + sred[1] + sred[2] + sred[3];
}

// ---------------------------------------------------------------------------
// GEMM: logits[n,m] = 2*sum_d q[n,d]*p[m,d] - p2[m], bf16 hi/lo 3-term.
//
// R10 (this round): pipelined double-buffer. Previous structure (R7, 111us,
// MfmaUtil 38.8, effective 928 TF = the documented ~900 TF 2-barrier-per-
// K-step ceiling) issued AND drained B's global_load_lds inside each K-step,
// and A's fp32-load->split->ds_write chain exposed a full HBM latency per
// step (MfmaUtil+VALUBusy = 62% -> 38% all-idle drain windows).
// Now: LDS double-buffered (64 KB), one barrier per K-step; at step kt we
//   - issue A(kt+1) fp32 loads into regs (consumed by split AFTER the MFMA
//     phase -> latency hidden; vmcnt counted by compiler, B stays in flight),
//   - issue B(kt+1) global_load_lds into buf^1 (drained by the barrier a
//     full compute-phase later),
//   - compute tile kt from buf, then split+ds_write A(kt+1), barrier.
// 4 waves/block (wave-tile 64x64, acc 4x4) -> 2 blocks/CU x 4 waves =
// 2 waves/SIMD. cur/nxt are literals (manual 2x unroll) so AA never orders
// gload_lds(buf^1) against ds_read(buf).
// Swizzles, fragment formulas (R4/R7-verified), 3-term numerics and MFMA
// accumulation order are UNCHANGED -> absmax should be bit-identical.
// ---------------------------------------------------------------------------
__global__ __launch_bounds__(256, 2) void gemm_logits_kernel(
    const float* __restrict__ query,
    const unsigned short* __restrict__ ph, const unsigned short* __restrict__ pl,
    const float* __restrict__ p2, float* __restrict__ out) {
    __shared__ unsigned short sAh[2][128 * 32];   // 2 x 8 KB
    __shared__ unsigned short sAl[2][128 * 32];   // 2 x 8 KB
    __shared__ unsigned short sBh[2][128 * 32];   // 2 x 8 KB
    __shared__ unsigned short sBl[2][128 * 32];   // 2 x 8 KB  (64 KB total)

    const int tid = threadIdx.x;
    const int wave = tid >> 6;   // 0..3
    const int lane = tid & 63;
    const int wr = wave >> 1;    // wave row-half of the 128-row tile
    const int wc = wave & 1;     // wave col-half of the 128-col tile
    const int b = blockIdx.x;
    const int mt = (b >> 3) & 7;
    const int nt = (b & 7) | ((b >> 6) << 3);
    const int row0 = nt * 128;
    const int col0 = mt * 128;

    // B staging (R4-verified swizzle): 4 waves x 4 gload_lds.
    // wave0: hi sub0-3, wave1: lo sub0-3, wave2: hi sub4-7, wave3: lo sub4-7.
    const int rlB = lane >> 2;
    const int cioB = (lane & 3) ^ ((lane >> 3) & 3);
    const int halfB = wave & 1;
    const int sgrpB = wave >> 1;
    const unsigned short* gB = (halfB ? pl : ph)
        + (size_t)(col0 + sgrpB * 64 + rlB) * D_K + cioB * 8;

    // A staging: lane -> (row-in-subtile rlA, granule cA); wave handles
    // subtiles wave*2+s, s=0..1. Same swizzle formula as compute side.
    const int rlA = lane >> 2;          // 0..15
    const int cA = lane & 3;            // k-granule 0..3
    const float* gA = query + (size_t)(row0 + wave * 32 + rlA) * D_K + cA * 8;
    const int wroff = (4 * rlA + (cA ^ ((rlA >> 1) & 3))) * 8;  // shorts

    // fragment read offsets (swizzle-matched, conflict-free)
    const int rsel = lane & 15;
    const int kq = lane >> 4;
    const int fragoff = (4 * rsel + (kq ^ ((rsel >> 1) & 3))) * 8;

    floatx4 zero = {0.0f, 0.0f, 0.0f, 0.0f};
    floatx4 acc[4][4];
#pragma unroll
    for (int i = 0; i < 4; ++i)
#pragma unroll
        for (int j = 0; j < 4; ++j) acc[i][j] = zero;

    floatx4 f0[2], f1[2];   // A prefetch registers (16 VGPR)

    auto issueA = [&](int kb) {
#pragma unroll
        for (int s = 0; s < 2; ++s) {
            const float* p = gA + (size_t)(s * 16) * D_K + kb;
            f0[s] = *(const floatx4*)p;
            f1[s] = *(const floatx4*)(p + 4);
        }
    };
    auto issueB = [&](int kb, int buf) {
        unsigned short* dstB = halfB ? sBl[buf] : sBh[buf];
#pragma unroll
        for (int s = 0; s < 4; ++s)
            __builtin_amdgcn_global_load_lds(
                (const AS1 unsigned int*)(const void*)(gB + (size_t)(s * 16) * D_K + kb),
                (AS3 unsigned int*)(void*)(dstB + (sgrpB * 4 + s) * 512), 16, 0, 0);
    };
    auto writeA = [&](int buf) {
#pragma unroll
        for (int s = 0; s < 2; ++s) {
            uint4v hi, lo;
            split_chunk(f0[s], f1[s], &hi, &lo);
            const int off = (wave * 2 + s) * 512 + wroff;
            *(uint4v*)(sAh[buf] + off) = hi;
            *(uint4v*)(sAl[buf] + off) = lo;
        }
    };
    auto compute = [&](int buf) {
        bf16x8 ah[4], al[4];
#pragma unroll
        for (int i = 0; i < 4; ++i) {
            const int aoff = (wr * 4 + i) * 512 + fragoff;
            ah[i] = *(const bf16x8*)(sAh[buf] + aoff);
            al[i] = *(const bf16x8*)(sAl[buf] + aoff);
        }
#pragma unroll
        for (int j = 0; j < 4; ++j) {
            const int boff = (wc * 4 + j) * 512 + fragoff;
            bf16x8 bhj = *(const bf16x8*)(sBh[buf] + boff);
            bf16x8 blj = *(const bf16x8*)(sBl[buf] + boff);
#pragma unroll
            for (int i = 0; i < 4; ++i) {
                acc[i][j] = __builtin_amdgcn_mfma_f32_16x16x32_bf16(ah[i], bhj, acc[i][j], 0, 0, 0);
                acc[i][j] = __builtin_amdgcn_mfma_f32_16x16x32_bf16(ah[i], blj, acc[i][j], 0, 0, 0);
                acc[i][j] = __builtin_amdgcn_mfma_f32_16x16x32_bf16(al[i], bhj, acc[i][j], 0, 0, 0);
            }
        }
    };
    auto step = [&](int kb, int cur, int nxt) {
        issueA(kb);          // A(next) -> regs, consumed after compute
        issueB(kb, nxt);     // B(next) -> buf[nxt], drained at the barrier
        compute(cur);        // MFMA phase hides both latencies
        writeA(nxt);         // split waits only A's vmcnt (B stays in flight)
        __syncthreads();
    };

    // prologue: tile 0 -> buf0 (one exposed latency, once)
    issueA(0);
    issueB(0, 0);
    writeA(0);
    __syncthreads();

    // 31 pipelined steps: step kt computes tile kt, prefetches tile kt+1.
    for (int kt = 0; kt < 30; kt += 2) {
        step((kt + 1) * 32, 0, 1);
        step((kt + 2) * 32, 1, 0);
    }
    step(31 * 32, 0, 1);    // kt = 30
    compute(1);             // tile 31 (no prefetch)

    // ---- epilogue: logits = 2*qp - p2[col] ----
    // C layout (verified m89/m91): col = lane&15, row = (lane>>4)*4 + reg
#pragma unroll
    for (int j = 0; j < 4; ++j) {
        const int gc = col0 + wc * 64 + j * 16 + rsel;
        const float p2v = p2[gc];
#pragma unroll
        for (int i = 0; i < 4; ++i) {
            const int gr = row0 + wr * 64 + i * 16 + kq * 4;
#pragma unroll
            for (int r = 0; r < 4; ++r) {
                out[(size_t)(gr + r) * M_P + gc] = 2.0f * acc[i][j][r] - p2v;
            }
        }
    }
}

// ---------------------------------------------------------------------------
// Fallback (tiny workspace): naive fp32 logits + separate softmax.
// ---------------------------------------------------------------------------
__global__ __launch_bounds__(256) void naive_logits_kernel(
    const float* __restrict__ query, const float* __restrict__ proto,
    float* __restrict__ out) {
    __shared__ float qs[D_K];
    int n = blockIdx.x;
    int t = threadIdx.x;
    ((float4*)qs)[t] = ((const float4*)(query + (size_t)n * D_K))[t];
    __syncthreads();
    float acc[4] = {0.f, 0.f, 0.f, 0.f};
    float pp[4] = {0.f, 0.f, 0.f, 0.f};
    for (int d = 0; d < D_K; d += 4) {
        float4 qv = *(const float4*)(qs + d);
#pragma unroll
        for (int j = 0; j < 4; ++j) {
            const float4 pv = *(const float4*)(proto + (size_t)(t + 256 * j) * D_K + d);
            acc[j] += qv.x * pv.x + qv.y * pv.y + qv.z * pv.z + qv.w * pv.w;
            pp[j] += pv.x * pv.x + pv.y * pv.y + pv.z * pv.z + pv.w * pv.w;
        }
    }
#pragma unroll
    for (int j = 0; j < 4; ++j)
        out[(size_t)n * M_P + t + 256 * j] = 2.0f * acc[j] - pp[j];
}

// ---------------------------------------------------------------------------
// In-place row softmax, wave-per-row (no LDS/barriers). ~24 us measured.
// ---------------------------------------------------------------------------
__global__ __launch_bounds__(256) void softmax_kernel(float* __restrict__ out) {
    const int lane = threadIdx.x & 63;
    int n = blockIdx.x * 4 + (threadIdx.x >> 6);
    for (int it = 0; it < 2; ++it, n += 8192) {
        float* row = out + (size_t)n * M_P;
        floatx4 v[4];
#pragma unroll
        for (int k = 0; k < 4; ++k)
            v[k] = *((const floatx4*)row + k * 64 + lane);
        float mx = fmaxf(fmaxf(v[0].x, v[0].y), fmaxf(v[0].z, v[0].w));
#pragma unroll
        for (int k = 1; k < 4; ++k)
            mx = fmaxf(mx, fmaxf(fmaxf(v[k].x, v[k].y), fmaxf(v[k].z, v[k].w)));
#pragma unroll
        for (int off = 1; off < 64; off <<= 1) mx = fmaxf(mx, __shfl_xor(mx, off));
        float s = 0.0f;
#pragma unroll
        for (int k = 0; k < 4; ++k) {
            v[k].x = __expf(v[k].x - mx);
            v[k].y = __expf(v[k].y - mx);
            v[k].z = __expf(v[k].z - mx);
            v[k].w = __expf(v[k].w - mx);
            s += v[k].x + v[k].y + v[k].z + v[k].w;
        }
#pragma unroll
        for (int off = 1; off < 64; off <<= 1) s += __shfl_xor(s, off);
        const float inv = 1.0f / s;
#pragma unroll
        for (int k = 0; k < 4; ++k) {
            floatx4 o;
            o.x = v[k].x * inv; o.y = v[k].y * inv;
            o.z = v[k].z * inv; o.w = v[k].w * inv;
            __builtin_nontemporal_store(o, (floatx4*)row + k * 64 + lane);
        }
    }
}

extern "C" void kernel_launch(void* const* d_in, const int* in_sizes, int n_in,
                              void* d_out, int out_size, void* d_ws, size_t ws_size,
                              hipStream_t stream) {
    const float* query = (const float*)d_in[0];
    const float* proto = (const float*)d_in[1];
    float* out = (float*)d_out;

    const size_t pElems = (size_t)M_P * D_K;   // 1M
    const size_t needed = pElems * 2 * 2 + M_P * 4;  // ~4.2 MiB

    if (ws_size >= needed) {
        unsigned short* ph = (unsigned short*)d_ws;
        unsigned short* pl = ph + pElems;
        float* p2 = (float*)(pl + pElems);

        convert_proto_kernel<<<M_P, 256, 0, stream>>>(proto, ph, pl, p2);
        gemm_logits_kernel<<<(N_Q / 128) * (M_P / 128), 256, 0, stream>>>(
            query, ph, pl, p2, out);
    } else {
        naive_logits_kernel<<<N_Q, 256, 0, stream>>>(query, proto, out);
    }
    softmax_kernel<<<2048, 256, 0, stream>>>(out);
}

// Round 2
// 206.575 us; speedup vs baseline: 1.2121x; 1.2121x over previous
//
#include <hip/hip_runtime.h>
#include <stdint.h>

#define N_Q 16384
#define M_P 1024
#define D_K 1024

typedef __attribute__((ext_vector_type(8))) __bf16 bf16x8;
typedef __attribute__((ext_vector_type(4))) float floatx4;
typedef __attribute__((ext_vector_type(4))) unsigned int uint4v;

#define AS1 __attribute__((address_space(1)))
#define AS3 __attribute__((address_space(3)))

__device__ __forceinline__ unsigned short f2bf(float f) {
    unsigned int u = __float_as_uint(f);
    u += 0x7fffu + ((u >> 16) & 1u);   // round-to-nearest-even
    return (unsigned short)(u >> 16);
}
__device__ __forceinline__ float bf2f(unsigned short h) {
    return __uint_as_float(((unsigned int)h) << 16);
}

// Split 8 fp32 (one k-chunk) -> packed bf16 hi (16B) + lo (16B).
// v_perm packs two hi-halves per instruction; trunc-hi + residual-lo
// (total rel err ~2^-16 per element -> logit err ~1e-3).
__device__ __forceinline__ void split_chunk(floatx4 f0, floatx4 f1,
                                            uint4v* hi, uint4v* lo) {
    float e[8] = {f0.x, f0.y, f0.z, f0.w, f1.x, f1.y, f1.z, f1.w};
    unsigned int hb[4], lb[4];
#pragma unroll
    for (int p = 0; p < 4; ++p) {
        unsigned int u0 = __float_as_uint(e[2 * p]);
        unsigned int u1 = __float_as_uint(e[2 * p + 1]);
        hb[p] = __builtin_amdgcn_perm(u1, u0, 0x07060302);  // [u0>>16, u1>>16]
        float l0 = e[2 * p]     - __uint_as_float(u0 & 0xffff0000u);
        float l1 = e[2 * p + 1] - __uint_as_float(u1 & 0xffff0000u);
        lb[p] = __builtin_amdgcn_perm(__float_as_uint(l1), __float_as_uint(l0),
                                      0x07060302);
    }
    uint4v h = {hb[0], hb[1], hb[2], hb[3]};
    uint4v l = {lb[0], lb[1], lb[2], lb[3]};
    *hi = h;
    *lo = l;
}

// ---------------------------------------------------------------------------
// Proto convert: split fp32 -> bf16 hi/lo + p2[m]. One block per row. ~5 us.
// ---------------------------------------------------------------------------
__global__ __launch_bounds__(256) void convert_proto_kernel(
    const float* __restrict__ proto, unsigned short* __restrict__ ph,
    unsigned short* __restrict__ pl, float* __restrict__ p2) {
    __shared__ float sred[4];
    int m = blockIdx.x;
    int t = threadIdx.x;
    size_t base4 = (size_t)m * (D_K / 4) + t;
    float4 v = ((const float4*)proto)[base4];
    ushort4 h, l;
    h.x = f2bf(v.x); l.x = f2bf(v.x - bf2f(h.x));
    h.y = f2bf(v.y); l.y = f2bf(v.y - bf2f(h.y));
    h.z = f2bf(v.z); l.z = f2bf(v.z - bf2f(h.z));
    h.w = f2bf(v.w); l.w = f2bf(v.w - bf2f(h.w));
    ((ushort4*)ph)[base4] = h;
    ((ushort4*)pl)[base4] = l;
    float sq = v.x * v.x + v.y * v.y + v.z * v.z + v.w * v.w;
#pragma unroll
    for (int off = 1; off < 64; off <<= 1) sq += __shfl_xor(sq, off);
    if ((t & 63) == 0) sred[t >> 6] = sq;
    __syncthreads();
    if (t == 0) p2[m] = sred[0] + sred[1] + sred[2] + sred[3];
}

// ---------------------------------------------------------------------------
// GEMM: logits[n,m] = 2*sum_d q[n,d]*p[m,d] - p2[m], bf16 hi/lo 3-term.
//
// R11: m201-style 8-phase structure. R10's lesson (151us, MfmaUtil 28.5):
// 64KB LDS at 2-barrier structure = m132 regression (occupancy-funded).
// The documented way past the ~900TF 2-barrier ceiling is the 256^2-tile
// phased schedule (T3+T4, m194-m201: 1563 TF) with T5 setprio (m218b).
//
// Geometry: BM=BN=256, BK=32(real k), 8 waves (2Mx4N, wave-tile 128x64),
// LDS = 2dbuf x {Ah,Al,Bh,Bl} x 256x32x2B = 128 KB, grid 64x4=256 = 1/CU.
// Per K-step: 4 phases x 24 MFMA (i-pair per phase; 3-term); raw s_barrier
// between phases (scheduling only), ONE __syncthreads per step (the only
// correctness barrier: all intra-step LDS traffic is buffer-disjoint).
// Staging for kt+1 issued at step top: A fp32->regs (consumed by
// split+ds_write at phases 2-3 -> ~3 phases of latency cover, T14), B via
// global_load_lds into buf^1 (in flight across 3 MFMA phases, drained by
// the step-end __syncthreads -> never drained in the phase it was issued).
// Swizzles/fragments/3-term MFMA chain identical to R7 -> absmax unchanged.
// XCD swizzle: b%8=XCD chunk of 32 consecutive row-tiles sharing one B
// col-panel (1MB hi+lo -> L2-resident per XCD).
// ---------------------------------------------------------------------------
__global__ __launch_bounds__(512, 2) void gemm_logits_kernel(
    const float* __restrict__ query,
    const unsigned short* __restrict__ ph, const unsigned short* __restrict__ pl,
    const float* __restrict__ p2, float* __restrict__ out) {
    __shared__ unsigned short sAh[2][16 * 512];   // 2 x 16 KB
    __shared__ unsigned short sAl[2][16 * 512];   // 2 x 16 KB
    __shared__ unsigned short sBh[2][16 * 512];   // 2 x 16 KB
    __shared__ unsigned short sBl[2][16 * 512];   // 2 x 16 KB  (128 KB)

    const int tid = threadIdx.x;
    const int wave = tid >> 6;   // 0..7
    const int lane = tid & 63;
    const int wr = wave >> 2;    // 0..1: row half (128 rows)
    const int wc = wave & 3;     // 0..3: col quarter (64 cols)

    // XCD-aware: 8 chunks of 32 blocks; chunk = same col-tile, 32 row-tiles.
    const int b = blockIdx.x;            // 0..255
    const int v = (b & 7) * 32 + (b >> 3);
    const int colt = v >> 6;             // 0..3
    const int rowt = v & 63;             // 0..63
    const int row0 = rowt * 256;
    const int col0 = colt * 256;

    // B staging (R4-verified pre-swizzled source, linear gload_lds dest):
    // waves 0-3 -> hi subtiles 4w..4w+3, waves 4-7 -> lo.
    const int rlB = lane >> 2;
    const int cioB = (lane & 3) ^ ((lane >> 3) & 3);
    const int halfB = wave >> 2;         // 0: hi, 1: lo
    const int sgB = wave & 3;
    const unsigned short* gB = (halfB ? pl : ph)
        + (size_t)(col0 + sgB * 64 + rlB) * D_K + cioB * 8;

    // A staging: wave covers rows wave*32..wave*32+31 (2 subtiles of 16).
    const int rlA = lane >> 2;          // 0..15
    const int cA = lane & 3;            // k-granule 0..3
    const float* gA = query + (size_t)(row0 + wave * 32 + rlA) * D_K + cA * 8;
    const int wroff = (4 * rlA + (cA ^ ((rlA >> 1) & 3))) * 8;  // shorts

    // fragment read offsets (swizzle-matched, conflict-free, R4-verified)
    const int rsel = lane & 15;
    const int kq = lane >> 4;
    const int fragoff = (4 * rsel + (kq ^ ((rsel >> 1) & 3))) * 8;

    floatx4 zero = {0.0f, 0.0f, 0.0f, 0.0f};
    floatx4 acc[8][4];
#pragma unroll
    for (int i = 0; i < 8; ++i)
#pragma unroll
        for (int j = 0; j < 4; ++j) acc[i][j] = zero;

    floatx4 f0[2], f1[2];        // A prefetch regs (16 VGPR)
    bf16x8 bh[4], bl[4];         // B fragments (held one K-step)
    bf16x8 ah[2], al[2];         // A fragments (per phase)

    auto issueA = [&](int kb) {
#pragma unroll
        for (int s = 0; s < 2; ++s) {
            const float* p = gA + (size_t)(s * 16) * D_K + kb;
            f0[s] = *(const floatx4*)p;
            f1[s] = *(const floatx4*)(p + 4);
        }
    };
    auto issueB = [&](int kb, int nxt) {
        unsigned short* dstB = (halfB ? sBl[nxt] : sBh[nxt]) + sgB * 4 * 512;
#pragma unroll
        for (int s = 0; s < 4; ++s)
            __builtin_amdgcn_global_load_lds(
                (const AS1 unsigned int*)(const void*)(gB + (size_t)(s * 16) * D_K + kb),
                (AS3 unsigned int*)(void*)(dstB + s * 512), 16, 0, 0);
    };
    auto writeA = [&](int nxt, int s) {
        uint4v hi, lo;
        split_chunk(f0[s], f1[s], &hi, &lo);
        const int off = (wave * 2 + s) * 512 + wroff;
        *(uint4v*)(sAh[nxt] + off) = hi;
        *(uint4v*)(sAl[nxt] + off) = lo;
    };
    auto ldBfrag = [&](int cur) {
#pragma unroll
        for (int j = 0; j < 4; ++j) {
            const int boff = (wc * 4 + j) * 512 + fragoff;
            bh[j] = *(const bf16x8*)(sBh[cur] + boff);
            bl[j] = *(const bf16x8*)(sBl[cur] + boff);
        }
    };
    auto ldAfrag = [&](int cur, int i0) {
#pragma unroll
        for (int t = 0; t < 2; ++t) {
            const int aoff = (wr * 8 + i0 + t) * 512 + fragoff;
            ah[t] = *(const bf16x8*)(sAh[cur] + aoff);
            al[t] = *(const bf16x8*)(sAl[cur] + aoff);
        }
    };
    auto mfma2 = [&](int i0) {
#pragma unroll
        for (int j = 0; j < 4; ++j)
#pragma unroll
            for (int t = 0; t < 2; ++t) {
                acc[i0 + t][j] = __builtin_amdgcn_mfma_f32_16x16x32_bf16(ah[t], bh[j], acc[i0 + t][j], 0, 0, 0);
                acc[i0 + t][j] = __builtin_amdgcn_mfma_f32_16x16x32_bf16(ah[t], bl[j], acc[i0 + t][j], 0, 0, 0);
                acc[i0 + t][j] = __builtin_amdgcn_mfma_f32_16x16x32_bf16(al[t], bh[j], acc[i0 + t][j], 0, 0, 0);
            }
    };

    // One K-step: compute buf[cur], stage kt+1 into buf[nxt] (if pf).
    // Correctness rests solely on the per-step __syncthreads: all reads of
    // cur retire there (lgkmcnt 0) before the next step overwrites cur, and
    // all staging of nxt (gload_lds vmcnt + ds_write lgkm) drains there.
    auto stepf = [&](int kbn, int cur, int nxt, bool pf) {
        if (pf) { issueA(kbn); issueB(kbn, nxt); }
        ldBfrag(cur);
        ldAfrag(cur, 0);
        __builtin_amdgcn_s_barrier();
        __builtin_amdgcn_s_setprio(1); mfma2(0); __builtin_amdgcn_s_setprio(0);
        __builtin_amdgcn_s_barrier();
        ldAfrag(cur, 2);
        __builtin_amdgcn_s_barrier();
        __builtin_amdgcn_s_setprio(1); mfma2(2); __builtin_amdgcn_s_setprio(0);
        __builtin_amdgcn_s_barrier();
        ldAfrag(cur, 4);
        if (pf) writeA(nxt, 0);           // A-loads had ~2 phases in flight
        __builtin_amdgcn_s_barrier();
        __builtin_amdgcn_s_setprio(1); mfma2(4); __builtin_amdgcn_s_setprio(0);
        __builtin_amdgcn_s_barrier();
        ldAfrag(cur, 6);
        if (pf) writeA(nxt, 1);
        __syncthreads();                  // the one full drain per step
        __builtin_amdgcn_s_setprio(1); mfma2(6); __builtin_amdgcn_s_setprio(0);
        // next step's staging issue overlaps mfma2(6)
    };

    // prologue: tile 0 -> buf0 (one exposed latency, once)
    issueA(0);
    issueB(0, 0);
    writeA(0, 0);
    writeA(0, 1);
    __syncthreads();

    for (int kt = 0; kt < 30; kt += 2) {
        stepf((kt + 1) * 32, 0, 1, true);
        stepf((kt + 2) * 32, 1, 0, true);
    }
    stepf(31 * 32, 0, 1, true);   // kt=30: compute buf0, prefetch tile 31
    stepf(0, 1, 0, false);        // kt=31: compute buf1, no prefetch

    // ---- epilogue: logits = 2*qp - p2[col] ----
    // C layout (verified m89/m91): col = lane&15, row = (lane>>4)*4 + reg
#pragma unroll
    for (int j = 0; j < 4; ++j) {
        const int gc = col0 + wc * 64 + j * 16 + rsel;
        const float p2v = p2[gc];
#pragma unroll
        for (int i = 0; i < 8; ++i) {
            const int gr = row0 + wr * 128 + i * 16 + kq * 4;
#pragma unroll
            for (int r = 0; r < 4; ++r) {
                out[(size_t)(gr + r) * M_P + gc] = 2.0f * acc[i][j][r] - p2v;
            }
        }
    }
}

// ---------------------------------------------------------------------------
// Fallback (tiny workspace): naive fp32 logits + separate softmax.
// ---------------------------------------------------------------------------
__global__ __launch_bounds__(256) void naive_logits_kernel(
    const float* __restrict__ query, const float* __restrict__ proto,
    float* __restrict__ out) {
    __shared__ float qs[D_K];
    int n = blockIdx.x;
    int t = threadIdx.x;
    ((float4*)qs)[t] = ((const float4*)(query + (size_t)n * D_K))[t];
    __syncthreads();
    float acc[4] = {0.f, 0.f, 0.f, 0.f};
    float pp[4] = {0.f, 0.f, 0.f, 0.f};
    for (int d = 0; d < D_K; d += 4) {
        float4 qv = *(const float4*)(qs + d);
#pragma unroll
        for (int j = 0; j < 4; ++j) {
            const float4 pv = *(const float4*)(proto + (size_t)(t + 256 * j) * D_K + d);
            acc[j] += qv.x * pv.x + qv.y * pv.y + qv.z * pv.z + qv.w * pv.w;
            pp[j] += pv.x * pv.x + pv.y * pv.y + pv.z * pv.z + pv.w * pv.w;
        }
    }
#pragma unroll
    for (int j = 0; j < 4; ++j)
        out[(size_t)n * M_P + t + 256 * j] = 2.0f * acc[j] - pp[j];
}

// ---------------------------------------------------------------------------
// In-place row softmax, wave-per-row (no LDS/barriers). ~24 us measured.
// ---------------------------------------------------------------------------
__global__ __launch_bounds__(256) void softmax_kernel(float* __restrict__ out) {
    const int lane = threadIdx.x & 63;
    int n = blockIdx.x * 4 + (threadIdx.x >> 6);
    for (int it = 0; it < 2; ++it, n += 8192) {
        float* row = out + (size_t)n * M_P;
        floatx4 v[4];
#pragma unroll
        for (int k = 0; k < 4; ++k)
            v[k] = *((const floatx4*)row + k * 64 + lane);
        float mx = fmaxf(fmaxf(v[0].x, v[0].y), fmaxf(v[0].z, v[0].w));
#pragma unroll
        for (int k = 1; k < 4; ++k)
            mx = fmaxf(mx, fmaxf(fmaxf(v[k].x, v[k].y), fmaxf(v[k].z, v[k].w)));
#pragma unroll
        for (int off = 1; off < 64; off <<= 1) mx = fmaxf(mx, __shfl_xor(mx, off));
        float s = 0.0f;
#pragma unroll
        for (int k = 0; k < 4; ++k) {
            v[k].x = __expf(v[k].x - mx);
            v[k].y = __expf(v[k].y - mx);
            v[k].z = __expf(v[k].z - mx);
            v[k].w = __expf(v[k].w - mx);
            s += v[k].x + v[k].y + v[k].z + v[k].w;
        }
#pragma unroll
        for (int off = 1; off < 64; off <<= 1) s += __shfl_xor(s, off);
        const float inv = 1.0f / s;
#pragma unroll
        for (int k = 0; k < 4; ++k) {
            floatx4 o;
            o.x = v[k].x * inv; o.y = v[k].y * inv;
            o.z = v[k].z * inv; o.w = v[k].w * inv;
            __builtin_nontemporal_store(o, (floatx4*)row + k * 64 + lane);
        }
    }
}

extern "C" void kernel_launch(void* const* d_in, const int* in_sizes, int n_in,
                              void* d_out, int out_size, void* d_ws, size_t ws_size,
                              hipStream_t stream) {
    const float* query = (const float*)d_in[0];
    const float* proto = (const float*)d_in[1];
    float* out = (float*)d_out;

    const size_t pElems = (size_t)M_P * D_K;   // 1M
    const size_t needed = pElems * 2 * 2 + M_P * 4;  // ~4.2 MiB

    if (ws_size >= needed) {
        unsigned short* ph = (unsigned short*)d_ws;
        unsigned short* pl = ph + pElems;
        float* p2 = (float*)(pl + pElems);

        convert_proto_kernel<<<M_P, 256, 0, stream>>>(proto, ph, pl, p2);
        gemm_logits_kernel<<<(N_Q / 256) * (M_P / 256), 512, 0, stream>>>(
            query, ph, pl, p2, out);
    } else {
        naive_logits_kernel<<<N_Q, 256, 0, stream>>>(query, proto, out);
    }
    softmax_kernel<<<2048, 256, 0, stream>>>(out);
}

// Round 3
// 201.977 us; speedup vs baseline: 1.2397x; 1.0228x over previous
//
#include <hip/hip_runtime.h>
#include <stdint.h>

#define N_Q 16384
#define M_P 1024
#define D_K 1024

typedef __attribute__((ext_vector_type(8))) __bf16 bf16x8;
typedef __attribute__((ext_vector_type(4))) float floatx4;
typedef __attribute__((ext_vector_type(4))) unsigned int uint4v;

#define AS1 __attribute__((address_space(1)))
#define AS3 __attribute__((address_space(3)))

__device__ __forceinline__ unsigned short f2bf(float f) {
    unsigned int u = __float_as_uint(f);
    u += 0x7fffu + ((u >> 16) & 1u);   // round-to-nearest-even
    return (unsigned short)(u >> 16);
}
__device__ __forceinline__ float bf2f(unsigned short h) {
    return __uint_as_float(((unsigned int)h) << 16);
}

// Split 8 fp32 (one k-chunk) -> packed bf16 hi (16B) + lo (16B).
__device__ __forceinline__ void split_chunk(floatx4 f0, floatx4 f1,
                                            uint4v* hi, uint4v* lo) {
    float e[8] = {f0.x, f0.y, f0.z, f0.w, f1.x, f1.y, f1.z, f1.w};
    unsigned int hb[4], lb[4];
#pragma unroll
    for (int p = 0; p < 4; ++p) {
        unsigned int u0 = __float_as_uint(e[2 * p]);
        unsigned int u1 = __float_as_uint(e[2 * p + 1]);
        hb[p] = __builtin_amdgcn_perm(u1, u0, 0x07060302);  // [u0>>16, u1>>16]
        float l0 = e[2 * p]     - __uint_as_float(u0 & 0xffff0000u);
        float l1 = e[2 * p + 1] - __uint_as_float(u1 & 0xffff0000u);
        lb[p] = __builtin_amdgcn_perm(__float_as_uint(l1), __float_as_uint(l0),
                                      0x07060302);
    }
    uint4v h = {hb[0], hb[1], hb[2], hb[3]};
    uint4v l = {lb[0], lb[1], lb[2], lb[3]};
    *hi = h;
    *lo = l;
}

// ---------------------------------------------------------------------------
// Proto convert: split fp32 -> bf16 hi/lo + p2[m]. One block per row. ~5 us.
// ---------------------------------------------------------------------------
__global__ __launch_bounds__(256) void convert_proto_kernel(
    const float* __restrict__ proto, unsigned short* __restrict__ ph,
    unsigned short* __restrict__ pl, float* __restrict__ p2) {
    __shared__ float sred[4];
    int m = blockIdx.x;
    int t = threadIdx.x;
    size_t base4 = (size_t)m * (D_K / 4) + t;
    float4 v = ((const float4*)proto)[base4];
    ushort4 h, l;
    h.x = f2bf(v.x); l.x = f2bf(v.x - bf2f(h.x));
    h.y = f2bf(v.y); l.y = f2bf(v.y - bf2f(h.y));
    h.z = f2bf(v.z); l.z = f2bf(v.z - bf2f(h.z));
    h.w = f2bf(v.w); l.w = f2bf(v.w - bf2f(h.w));
    ((ushort4*)ph)[base4] = h;
    ((ushort4*)pl)[base4] = l;
    float sq = v.x * v.x + v.y * v.y + v.z * v.z + v.w * v.w;
#pragma unroll
    for (int off = 1; off < 64; off <<= 1) sq += __shfl_xor(sq, off);
    if ((t & 63) == 0) sred[t >> 6] = sq;
    __syncthreads();
    if (t == 0) p2[m] = sred[0] + sred[1] + sred[2] + sred[3];
}

// ---------------------------------------------------------------------------
// GEMM: logits[n,m] = 2*sum_d q[n,d]*p[m,d] - p2[m], bf16 hi/lo 3-term.
//
// R12: R11's shape + the ACTUAL m201 discipline R11 skipped.
// R11 post-mortem (108us, MfmaUtil 39.9 == R7): raw s_barriers without
// lgkmcnt-asm + sched_barrier(0) pinning let LLVM recluster all ds_reads ->
// phases collapsed back to the 1-phase schedule; per-step __syncthreads =
// drain0 (m218: 8-phase+drain0 == 1-phase; counted vmcnt IS the gain).
// Changes (schedule only -- swizzles/numerics/MFMA order bit-identical):
//  * per phase: s_barrier; asm lgkmcnt(0); sched_barrier(0); setprio(1);
//    24 MFMA; setprio(0); s_barrier   (pins the LDS/MFMA alternation)
//  * NO __syncthreads in loop; step end = lgkmcnt(0) [ds_write visibility]
//    + counted vmcnt(4) [4 B gload_lds oldest of exactly 8 outstanding]
//    + s_barrier. vmcnt(0) only at step 30 (epilogue drain, once).
//  * A-issue moved to phase 4 (after both writeA in phase 3) so vmem order
//    per step is strictly [B x4][A x4] -> counts are exact. A loads cast to
//    addrspace(1) so they hit vmcnt only (flat would also bump lgkmcnt).
//  * mfma2(6) after the end-of-step barrier: its drain overlaps next step's
//    B-issue + 12 ds_read segment.
// ---------------------------------------------------------------------------
__global__ __launch_bounds__(512, 2) void gemm_logits_kernel(
    const float* __restrict__ query,
    const unsigned short* __restrict__ ph, const unsigned short* __restrict__ pl,
    const float* __restrict__ p2, float* __restrict__ out) {
    __shared__ unsigned short sAh[2][16 * 512];   // 2 x 16 KB
    __shared__ unsigned short sAl[2][16 * 512];   // 2 x 16 KB
    __shared__ unsigned short sBh[2][16 * 512];   // 2 x 16 KB
    __shared__ unsigned short sBl[2][16 * 512];   // 2 x 16 KB  (128 KB)

    const int tid = threadIdx.x;
    const int wave = tid >> 6;   // 0..7
    const int lane = tid & 63;
    const int wr = wave >> 2;    // 0..1: row half (128 rows)
    const int wc = wave & 3;     // 0..3: col quarter (64 cols)

    // XCD-aware: 8 chunks of 32 blocks; chunk = same col-tile, 32 row-tiles.
    const int b = blockIdx.x;            // 0..255
    const int v = (b & 7) * 32 + (b >> 3);
    const int colt = v >> 6;             // 0..3
    const int rowt = v & 63;             // 0..63
    const int row0 = rowt * 256;
    const int col0 = colt * 256;

    // B staging (R4-verified pre-swizzled source, linear gload_lds dest):
    const int rlB = lane >> 2;
    const int cioB = (lane & 3) ^ ((lane >> 3) & 3);
    const int halfB = wave >> 2;         // 0: hi, 1: lo
    const int sgB = wave & 3;
    const unsigned short* gB = (halfB ? pl : ph)
        + (size_t)(col0 + sgB * 64 + rlB) * D_K + cioB * 8;

    // A staging: wave covers rows wave*32..wave*32+31 (2 subtiles of 16).
    const int rlA = lane >> 2;          // 0..15
    const int cA = lane & 3;            // k-granule 0..3
    const AS1 float* gA = (const AS1 float*)query
        + (size_t)(row0 + wave * 32 + rlA) * D_K + cA * 8;
    const int wroff = (4 * rlA + (cA ^ ((rlA >> 1) & 3))) * 8;  // shorts

    // fragment read offsets (swizzle-matched, conflict-free, R4-verified)
    const int rsel = lane & 15;
    const int kq = lane >> 4;
    const int fragoff = (4 * rsel + (kq ^ ((rsel >> 1) & 3))) * 8;

    floatx4 zero = {0.0f, 0.0f, 0.0f, 0.0f};
    floatx4 acc[8][4];
#pragma unroll
    for (int i = 0; i < 8; ++i)
#pragma unroll
        for (int j = 0; j < 4; ++j) acc[i][j] = zero;

    floatx4 f0[2], f1[2];        // A prefetch regs (16 VGPR)
    bf16x8 bh[4], bl[4];         // B fragments (held one K-step)
    bf16x8 ah[2], al[2];         // A fragments (per phase)

    auto issueA = [&](int kb) {
#pragma unroll
        for (int s = 0; s < 2; ++s) {
            const AS1 float* p = gA + (size_t)(s * 16) * D_K + kb;
            f0[s] = *(const AS1 floatx4*)p;
            f1[s] = *(const AS1 floatx4*)(p + 4);
        }
    };
    auto issueB = [&](int kb, int nxt) {
        unsigned short* dstB = (halfB ? sBl[nxt] : sBh[nxt]) + sgB * 4 * 512;
#pragma unroll
        for (int s = 0; s < 4; ++s)
            __builtin_amdgcn_global_load_lds(
                (const AS1 unsigned int*)(const void*)(gB + (size_t)(s * 16) * D_K + kb),
                (AS3 unsigned int*)(void*)(dstB + s * 512), 16, 0, 0);
    };
    auto writeA = [&](int nxt, int s) {
        uint4v hi, lo;
        split_chunk(f0[s], f1[s], &hi, &lo);
        const int off = (wave * 2 + s) * 512 + wroff;
        *(uint4v*)(sAh[nxt] + off) = hi;
        *(uint4v*)(sAl[nxt] + off) = lo;
    };
    auto ldBfrag = [&](int cur) {
#pragma unroll
        for (int j = 0; j < 4; ++j) {
            const int boff = (wc * 4 + j) * 512 + fragoff;
            bh[j] = *(const bf16x8*)(sBh[cur] + boff);
            bl[j] = *(const bf16x8*)(sBl[cur] + boff);
        }
    };
    auto ldAfrag = [&](int cur, int i0) {
#pragma unroll
        for (int t = 0; t < 2; ++t) {
            const int aoff = (wr * 8 + i0 + t) * 512 + fragoff;
            ah[t] = *(const bf16x8*)(sAh[cur] + aoff);
            al[t] = *(const bf16x8*)(sAl[cur] + aoff);
        }
    };
    auto mfma2 = [&](int i0) {
#pragma unroll
        for (int j = 0; j < 4; ++j)
#pragma unroll
            for (int t = 0; t < 2; ++t) {
                acc[i0 + t][j] = __builtin_amdgcn_mfma_f32_16x16x32_bf16(ah[t], bh[j], acc[i0 + t][j], 0, 0, 0);
                acc[i0 + t][j] = __builtin_amdgcn_mfma_f32_16x16x32_bf16(ah[t], bl[j], acc[i0 + t][j], 0, 0, 0);
                acc[i0 + t][j] = __builtin_amdgcn_mfma_f32_16x16x32_bf16(al[t], bh[j], acc[i0 + t][j], 0, 0, 0);
            }
    };

#define PHASE_MFMA(i0)                                          \
    __builtin_amdgcn_s_barrier();                               \
    asm volatile("s_waitcnt lgkmcnt(0)" ::: "memory");          \
    __builtin_amdgcn_sched_barrier(0);                          \
    __builtin_amdgcn_s_setprio(1);                              \
    mfma2(i0);                                                  \
    __builtin_amdgcn_s_setprio(0);                              \
    __builtin_amdgcn_s_barrier();

    // One K-step. Vmem issue order per step: [B x4 gload_lds][A x4 loads]
    // -> writeA's reg-dep wait is vmcnt(4) (compiler-counted), end-of-step
    // B-landed wait is vmcnt(4) (ours). Never 0 until step 30.
    auto stepf = [&](int kbnB, int kbnA, int cur, int nxt, bool pfB, bool pfA) {
        if (pfB) issueB(kbnB, nxt);
        ldBfrag(cur);
        ldAfrag(cur, 0);
        PHASE_MFMA(0)
        ldAfrag(cur, 2);
        PHASE_MFMA(2)
        ldAfrag(cur, 4);
        if (pfB) { writeA(nxt, 0); writeA(nxt, 1); }
        PHASE_MFMA(4)
        ldAfrag(cur, 6);
        if (pfA) issueA(kbnA);
        asm volatile("s_waitcnt lgkmcnt(0)" ::: "memory");
        if (pfB) {
            if (pfA) asm volatile("s_waitcnt vmcnt(4)" ::: "memory");
            else     asm volatile("s_waitcnt vmcnt(0)" ::: "memory");
        }
        __builtin_amdgcn_s_barrier();
        __builtin_amdgcn_sched_barrier(0);
        __builtin_amdgcn_s_setprio(1);
        mfma2(6);
        __builtin_amdgcn_s_setprio(0);
    };

    // prologue: tile 0 -> buf0; prefetch A(t1).
    issueA(0);                  // A(t0): oldest 4
    issueB(0, 0);               // B(t0): next 4
    writeA(0, 0);               // compiler waits vmcnt(4): A(t0) done, B in flight
    writeA(0, 1);
    issueA(32);                 // A(t1) (WAR on f regs vs the 4 ds_writes: ~40cy, once)
    asm volatile("s_waitcnt lgkmcnt(0)" ::: "memory");
    asm volatile("s_waitcnt vmcnt(4)" ::: "memory");   // B(t0) landed, A(t1) in flight
    __builtin_amdgcn_s_barrier();

    for (int kt = 0; kt < 30; kt += 2) {
        stepf((kt + 1) * 32, (kt + 2) * 32, 0, 1, true, true);
        stepf((kt + 2) * 32, (kt + 3) * 32, 1, 0, true, true);
    }
    stepf(31 * 32, 0, 0, 1, true, false);   // kt=30: stage t31, drain vmcnt(0)
    stepf(0, 0, 1, 0, false, false);        // kt=31: compute only

#undef PHASE_MFMA

    // ---- epilogue: logits = 2*qp - p2[col] ----
    // C layout (verified m89/m91): col = lane&15, row = (lane>>4)*4 + reg
#pragma unroll
    for (int j = 0; j < 4; ++j) {
        const int gc = col0 + wc * 64 + j * 16 + rsel;
        const float p2v = p2[gc];
#pragma unroll
        for (int i = 0; i < 8; ++i) {
            const int gr = row0 + wr * 128 + i * 16 + kq * 4;
#pragma unroll
            for (int r = 0; r < 4; ++r) {
                out[(size_t)(gr + r) * M_P + gc] = 2.0f * acc[i][j][r] - p2v;
            }
        }
    }
}

// ---------------------------------------------------------------------------
// Fallback (tiny workspace): naive fp32 logits + separate softmax.
// ---------------------------------------------------------------------------
__global__ __launch_bounds__(256) void naive_logits_kernel(
    const float* __restrict__ query, const float* __restrict__ proto,
    float* __restrict__ out) {
    __shared__ float qs[D_K];
    int n = blockIdx.x;
    int t = threadIdx.x;
    ((float4*)qs)[t] = ((const float4*)(query + (size_t)n * D_K))[t];
    __syncthreads();
    float acc[4] = {0.f, 0.f, 0.f, 0.f};
    float pp[4] = {0.f, 0.f, 0.f, 0.f};
    for (int d = 0; d < D_K; d += 4) {
        float4 qv = *(const float4*)(qs + d);
#pragma unroll
        for (int j = 0; j < 4; ++j) {
            const float4 pv = *(const float4*)(proto + (size_t)(t + 256 * j) * D_K + d);
            acc[j] += qv.x * pv.x + qv.y * pv.y + qv.z * pv.z + qv.w * pv.w;
            pp[j] += pv.x * pv.x + pv.y * pv.y + pv.z * pv.z + pv.w * pv.w;
        }
    }
#pragma unroll
    for (int j = 0; j < 4; ++j)
        out[(size_t)n * M_P + t + 256 * j] = 2.0f * acc[j] - pp[j];
}

// ---------------------------------------------------------------------------
// In-place row softmax, wave-per-row (no LDS/barriers). ~24 us measured.
// ---------------------------------------------------------------------------
__global__ __launch_bounds__(256) void softmax_kernel(float* __restrict__ out) {
    const int lane = threadIdx.x & 63;
    int n = blockIdx.x * 4 + (threadIdx.x >> 6);
    for (int it = 0; it < 2; ++it, n += 8192) {
        float* row = out + (size_t)n * M_P;
        floatx4 v[4];
#pragma unroll
        for (int k = 0; k < 4; ++k)
            v[k] = *((const floatx4*)row + k * 64 + lane);
        float mx = fmaxf(fmaxf(v[0].x, v[0].y), fmaxf(v[0].z, v[0].w));
#pragma unroll
        for (int k = 1; k < 4; ++k)
            mx = fmaxf(mx, fmaxf(fmaxf(v[k].x, v[k].y), fmaxf(v[k].z, v[k].w)));
#pragma unroll
        for (int off = 1; off < 64; off <<= 1) mx = fmaxf(mx, __shfl_xor(mx, off));
        float s = 0.0f;
#pragma unroll
        for (int k = 0; k < 4; ++k) {
            v[k].x = __expf(v[k].x - mx);
            v[k].y = __expf(v[k].y - mx);
            v[k].z = __expf(v[k].z - mx);
            v[k].w = __expf(v[k].w - mx);
            s += v[k].x + v[k].y + v[k].z + v[k].w;
        }
#pragma unroll
        for (int off = 1; off < 64; off <<= 1) s += __shfl_xor(s, off);
        const float inv = 1.0f / s;
#pragma unroll
        for (int k = 0; k < 4; ++k) {
            floatx4 o;
            o.x = v[k].x * inv; o.y = v[k].y * inv;
            o.z = v[k].z * inv; o.w = v[k].w * inv;
            __builtin_nontemporal_store(o, (floatx4*)row + k * 64 + lane);
        }
    }
}

extern "C" void kernel_launch(void* const* d_in, const int* in_sizes, int n_in,
                              void* d_out, int out_size, void* d_ws, size_t ws_size,
                              hipStream_t stream) {
    const float* query = (const float*)d_in[0];
    const float* proto = (const float*)d_in[1];
    float* out = (float*)d_out;

    const size_t pElems = (size_t)M_P * D_K;   // 1M
    const size_t needed = pElems * 2 * 2 + M_P * 4;  // ~4.2 MiB

    if (ws_size >= needed) {
        unsigned short* ph = (unsigned short*)d_ws;
        unsigned short* pl = ph + pElems;
        float* p2 = (float*)(pl + pElems);

        convert_proto_kernel<<<M_P, 256, 0, stream>>>(proto, ph, pl, p2);
        gemm_logits_kernel<<<(N_Q / 256) * (M_P / 256), 512, 0, stream>>>(
            query, ph, pl, p2, out);
    } else {
        naive_logits_kernel<<<N_Q, 256, 0, stream>>>(query, proto, out);
    }
    softmax_kernel<<<2048, 256, 0, stream>>>(out);
}

// Round 4
// 198.139 us; speedup vs baseline: 1.2637x; 1.0194x over previous
//
#include <hip/hip_runtime.h>
#include <stdint.h>

#define N_Q 16384
#define M_P 1024
#define D_K 1024

typedef __attribute__((ext_vector_type(8))) __bf16 bf16x8;
typedef __attribute__((ext_vector_type(4))) float floatx4;
typedef __attribute__((ext_vector_type(4))) unsigned int uint4v;

#define AS1 __attribute__((address_space(1)))
#define AS3 __attribute__((address_space(3)))

__device__ __forceinline__ unsigned short f2bf(float f) {
    unsigned int u = __float_as_uint(f);
    u += 0x7fffu + ((u >> 16) & 1u);   // round-to-nearest-even
    return (unsigned short)(u >> 16);
}
__device__ __forceinline__ float bf2f(unsigned short h) {
    return __uint_as_float(((unsigned int)h) << 16);
}

// Split 8 fp32 (one k-chunk) -> packed bf16 hi (16B) + lo (16B).
__device__ __forceinline__ void split_chunk(floatx4 f0, floatx4 f1,
                                            uint4v* hi, uint4v* lo) {
    float e[8] = {f0.x, f0.y, f0.z, f0.w, f1.x, f1.y, f1.z, f1.w};
    unsigned int hb[4], lb[4];
#pragma unroll
    for (int p = 0; p < 4; ++p) {
        unsigned int u0 = __float_as_uint(e[2 * p]);
        unsigned int u1 = __float_as_uint(e[2 * p + 1]);
        hb[p] = __builtin_amdgcn_perm(u1, u0, 0x07060302);  // [u0>>16, u1>>16]
        float l0 = e[2 * p]     - __uint_as_float(u0 & 0xffff0000u);
        float l1 = e[2 * p + 1] - __uint_as_float(u1 & 0xffff0000u);
        lb[p] = __builtin_amdgcn_perm(__float_as_uint(l1), __float_as_uint(l0),
                                      0x07060302);
    }
    uint4v h = {hb[0], hb[1], hb[2], hb[3]};
    uint4v l = {lb[0], lb[1], lb[2], lb[3]};
    *hi = h;
    *lo = l;
}

// ---------------------------------------------------------------------------
// Proto convert: split fp32 -> bf16 hi/lo + p2[m]. One block per row. ~5 us.
// ---------------------------------------------------------------------------
__global__ __launch_bounds__(256) void convert_proto_kernel(
    const float* __restrict__ proto, unsigned short* __restrict__ ph,
    unsigned short* __restrict__ pl, float* __restrict__ p2) {
    __shared__ float sred[4];
    int m = blockIdx.x;
    int t = threadIdx.x;
    size_t base4 = (size_t)m * (D_K / 4) + t;
    float4 v = ((const float4*)proto)[base4];
    ushort4 h, l;
    h.x = f2bf(v.x); l.x = f2bf(v.x - bf2f(h.x));
    h.y = f2bf(v.y); l.y = f2bf(v.y - bf2f(h.y));
    h.z = f2bf(v.z); l.z = f2bf(v.z - bf2f(h.z));
    h.w = f2bf(v.w); l.w = f2bf(v.w - bf2f(h.w));
    ((ushort4*)ph)[base4] = h;
    ((ushort4*)pl)[base4] = l;
    float sq = v.x * v.x + v.y * v.y + v.z * v.z + v.w * v.w;
#pragma unroll
    for (int off = 1; off < 64; off <<= 1) sq += __shfl_xor(sq, off);
    if ((t & 63) == 0) sred[t >> 6] = sq;
    __syncthreads();
    if (t == 0) p2[m] = sred[0] + sred[1] + sred[2] + sred[3];
}

// ---------------------------------------------------------------------------
// GEMM: logits[n,m] = 2*sum_d q[n,d]*p[m,d] - p2[m], bf16 hi/lo 3-term.
//
// R13: counted-LGKM read-ahead, ONE barrier per K-step.
// R12 post-mortem (104us, MfmaUtil 41.6): cycle model FITS measurement --
// per-CU step = LDS reads 768 + writes 250 + MFMA/SIMD 932 + VALU split 240
// + 8 barriers ~= 2270 cyc = measured. Lockstep phases with lgkmcnt(0)
// serialize EVERYTHING; MfmaUtil 932/2270 = 41%. m218's lesson applied to
// the lgkm pipe: counted waits + loads-in-flight-across-compute.
// Changes (schedule only; swizzles/numerics/MFMA order bit-identical):
//  * A-fragments double-buffered in regs (2 sets); each phase's 4 ds_reads
//    issued one phase EARLY; wait lgkmcnt(4) (reads-only FIFO, m201's exact
//    pattern) + sched_barrier(0) (rule 18) -> LDS service overlaps MFMA.
//  * NO intra-step barriers: one s_barrier at step end. Correctness: all
//    buf[cur] reads retire at the final lgkmcnt(0) before the barrier; all
//    buf[nxt] staging (4 gload_lds B, vmcnt-counted; 4 ds_write A, lgkm)
//    drains before it. Wave drift inside the step lets the split-VALU of
//    one wave overlap the other wave's MFMA (m114).
//  * writeA moved after MFMA(4): every counted lgkm wait covers READS only
//    (ds-read FIFO is solid); writes retire at the final lgkmcnt(0).
//  * vmcnt discipline unchanged from R12: per-step issue [B x4][A x4],
//    end-of-step vmcnt(4), vmcnt(0) only at step 30.
// ---------------------------------------------------------------------------
__global__ __launch_bounds__(512, 2) void gemm_logits_kernel(
    const float* __restrict__ query,
    const unsigned short* __restrict__ ph, const unsigned short* __restrict__ pl,
    const float* __restrict__ p2, float* __restrict__ out) {
    __shared__ unsigned short sAh[2][16 * 512];   // 2 x 16 KB
    __shared__ unsigned short sAl[2][16 * 512];   // 2 x 16 KB
    __shared__ unsigned short sBh[2][16 * 512];   // 2 x 16 KB
    __shared__ unsigned short sBl[2][16 * 512];   // 2 x 16 KB  (128 KB)

    const int tid = threadIdx.x;
    const int wave = tid >> 6;   // 0..7
    const int lane = tid & 63;
    const int wr = wave >> 2;    // 0..1: row half (128 rows)
    const int wc = wave & 3;     // 0..3: col quarter (64 cols)

    // XCD-aware: 8 chunks of 32 blocks; chunk = same col-tile, 32 row-tiles.
    const int b = blockIdx.x;            // 0..255
    const int v = (b & 7) * 32 + (b >> 3);
    const int colt = v >> 6;             // 0..3
    const int rowt = v & 63;             // 0..63
    const int row0 = rowt * 256;
    const int col0 = colt * 256;

    // B staging (R4-verified pre-swizzled source, linear gload_lds dest):
    const int rlB = lane >> 2;
    const int cioB = (lane & 3) ^ ((lane >> 3) & 3);
    const int halfB = wave >> 2;         // 0: hi, 1: lo
    const int sgB = wave & 3;
    const unsigned short* gB = (halfB ? pl : ph)
        + (size_t)(col0 + sgB * 64 + rlB) * D_K + cioB * 8;

    // A staging: wave covers rows wave*32..wave*32+31 (2 subtiles of 16).
    const int rlA = lane >> 2;          // 0..15
    const int cA = lane & 3;            // k-granule 0..3
    const AS1 float* gA = (const AS1 float*)query
        + (size_t)(row0 + wave * 32 + rlA) * D_K + cA * 8;
    const int wroff = (4 * rlA + (cA ^ ((rlA >> 1) & 3))) * 8;  // shorts

    // fragment read offsets (swizzle-matched, conflict-free, R4-verified)
    const int rsel = lane & 15;
    const int kq = lane >> 4;
    const int fragoff = (4 * rsel + (kq ^ ((rsel >> 1) & 3))) * 8;

    floatx4 zero = {0.0f, 0.0f, 0.0f, 0.0f};
    floatx4 acc[8][4];
#pragma unroll
    for (int i = 0; i < 8; ++i)
#pragma unroll
        for (int j = 0; j < 4; ++j) acc[i][j] = zero;

    floatx4 f0[2], f1[2];        // A prefetch regs (16 VGPR)
    bf16x8 bh[4], bl[4];         // B fragments (held one K-step)
    bf16x8 ah[2][2], al[2][2];   // A fragments, 2 reg-sets (read-ahead)

    auto issueA = [&](int kb) {
#pragma unroll
        for (int s = 0; s < 2; ++s) {
            const AS1 float* p = gA + (size_t)(s * 16) * D_K + kb;
            f0[s] = *(const AS1 floatx4*)p;
            f1[s] = *(const AS1 floatx4*)(p + 4);
        }
    };
    auto issueB = [&](int kb, int nxt) {
        unsigned short* dstB = (halfB ? sBl[nxt] : sBh[nxt]) + sgB * 4 * 512;
#pragma unroll
        for (int s = 0; s < 4; ++s)
            __builtin_amdgcn_global_load_lds(
                (const AS1 unsigned int*)(const void*)(gB + (size_t)(s * 16) * D_K + kb),
                (AS3 unsigned int*)(void*)(dstB + s * 512), 16, 0, 0);
    };
    auto writeA = [&](int nxt, int s) {
        uint4v hi, lo;
        split_chunk(f0[s], f1[s], &hi, &lo);
        const int off = (wave * 2 + s) * 512 + wroff;
        *(uint4v*)(sAh[nxt] + off) = hi;
        *(uint4v*)(sAl[nxt] + off) = lo;
    };
    auto ldBfrag = [&](int cur) {
#pragma unroll
        for (int j = 0; j < 4; ++j) {
            const int boff = (wc * 4 + j) * 512 + fragoff;
            bh[j] = *(const bf16x8*)(sBh[cur] + boff);
            bl[j] = *(const bf16x8*)(sBl[cur] + boff);
        }
    };
    // load A-frag pair (i0, i0+1) into reg-set `set` (literal at all sites)
    auto ldA = [&](int cur, int i0, int set) {
#pragma unroll
        for (int t = 0; t < 2; ++t) {
            const int aoff = (wr * 8 + i0 + t) * 512 + fragoff;
            ah[set][t] = *(const bf16x8*)(sAh[cur] + aoff);
            al[set][t] = *(const bf16x8*)(sAl[cur] + aoff);
        }
    };
    auto mfma2 = [&](int i0, int set) {
#pragma unroll
        for (int j = 0; j < 4; ++j)
#pragma unroll
            for (int t = 0; t < 2; ++t) {
                acc[i0 + t][j] = __builtin_amdgcn_mfma_f32_16x16x32_bf16(ah[set][t], bh[j], acc[i0 + t][j], 0, 0, 0);
                acc[i0 + t][j] = __builtin_amdgcn_mfma_f32_16x16x32_bf16(ah[set][t], bl[j], acc[i0 + t][j], 0, 0, 0);
                acc[i0 + t][j] = __builtin_amdgcn_mfma_f32_16x16x32_bf16(al[set][t], bh[j], acc[i0 + t][j], 0, 0, 0);
            }
    };

#define LGKM_MFMA(n, i0, set)                                   \
    asm volatile("s_waitcnt lgkmcnt(" #n ")" ::: "memory");     \
    __builtin_amdgcn_sched_barrier(0);                          \
    __builtin_amdgcn_s_setprio(1);                              \
    mfma2(i0, set);                                             \
    __builtin_amdgcn_s_setprio(0);

    // One K-step. DS issue order: [B 8r][A01 4r][A23 4r] | [A45 4r] |
    // [A67 4r] | [W 4w]. Counted lgkm waits cover reads only (FIFO).
    // Vmem order: [B x4 gload_lds][A x4 loads]; end-of-step vmcnt(4).
    auto stepf = [&](int kbnB, int kbnA, int cur, int nxt, bool pfB, bool pfA) {
        if (pfB) issueB(kbnB, nxt);
        ldBfrag(cur);                // 8 reads
        ldA(cur, 0, 0);              // 4 reads
        ldA(cur, 2, 1);              // 4 reads   [16 outstanding]
        LGKM_MFMA(4, 0, 0)           // B+A01 done; A23 in flight under MFMA
        ldA(cur, 4, 0);              // [<=8 outstanding]
        LGKM_MFMA(4, 2, 1)           // A23 done; A45 in flight under MFMA
        ldA(cur, 6, 1);              // [<=8 outstanding]
        LGKM_MFMA(4, 4, 0)           // A45 done; A67 in flight under MFMA
        if (pfB) { writeA(nxt, 0); writeA(nxt, 1); }  // VALU + 4 ds_write
        if (pfA) issueA(kbnA);       // f-regs free after writeA
        asm volatile("s_waitcnt lgkmcnt(0)" ::: "memory");  // A67 + writes
        if (pfB) {
            if (pfA) asm volatile("s_waitcnt vmcnt(4)" ::: "memory");
            else     asm volatile("s_waitcnt vmcnt(0)" ::: "memory");
        }
        __builtin_amdgcn_sched_barrier(0);
        __builtin_amdgcn_s_setprio(1);
        mfma2(6, 1);
        __builtin_amdgcn_s_setprio(0);
        __builtin_amdgcn_s_barrier();   // the ONE barrier per step
    };

    // prologue: tile 0 -> buf0; prefetch A(t1).
    issueA(0);                  // A(t0): oldest 4
    issueB(0, 0);               // B(t0): next 4
    writeA(0, 0);               // compiler waits vmcnt(4): A(t0) done, B in flight
    writeA(0, 1);
    issueA(32);                 // A(t1) in flight across the barrier
    asm volatile("s_waitcnt lgkmcnt(0)" ::: "memory");
    asm volatile("s_waitcnt vmcnt(4)" ::: "memory");   // B(t0) landed
    __builtin_amdgcn_s_barrier();

    for (int kt = 0; kt < 30; kt += 2) {
        stepf((kt + 1) * 32, (kt + 2) * 32, 0, 1, true, true);
        stepf((kt + 2) * 32, (kt + 3) * 32, 1, 0, true, true);
    }
    stepf(31 * 32, 0, 0, 1, true, false);   // kt=30: stage t31, drain vmcnt(0)
    stepf(0, 0, 1, 0, false, false);        // kt=31: compute only

#undef LGKM_MFMA

    // ---- epilogue: logits = 2*qp - p2[col] ----
    // C layout (verified m89/m91): col = lane&15, row = (lane>>4)*4 + reg
#pragma unroll
    for (int j = 0; j < 4; ++j) {
        const int gc = col0 + wc * 64 + j * 16 + rsel;
        const float p2v = p2[gc];
#pragma unroll
        for (int i = 0; i < 8; ++i) {
            const int gr = row0 + wr * 128 + i * 16 + kq * 4;
#pragma unroll
            for (int r = 0; r < 4; ++r) {
                out[(size_t)(gr + r) * M_P + gc] = 2.0f * acc[i][j][r] - p2v;
            }
        }
    }
}

// ---------------------------------------------------------------------------
// Fallback (tiny workspace): naive fp32 logits + separate softmax.
// ---------------------------------------------------------------------------
__global__ __launch_bounds__(256) void naive_logits_kernel(
    const float* __restrict__ query, const float* __restrict__ proto,
    float* __restrict__ out) {
    __shared__ float qs[D_K];
    int n = blockIdx.x;
    int t = threadIdx.x;
    ((float4*)qs)[t] = ((const float4*)(query + (size_t)n * D_K))[t];
    __syncthreads();
    float acc[4] = {0.f, 0.f, 0.f, 0.f};
    float pp[4] = {0.f, 0.f, 0.f, 0.f};
    for (int d = 0; d < D_K; d += 4) {
        float4 qv = *(const float4*)(qs + d);
#pragma unroll
        for (int j = 0; j < 4; ++j) {
            const float4 pv = *(const float4*)(proto + (size_t)(t + 256 * j) * D_K + d);
            acc[j] += qv.x * pv.x + qv.y * pv.y + qv.z * pv.z + qv.w * pv.w;
            pp[j] += pv.x * pv.x + pv.y * pv.y + pv.z * pv.z + pv.w * pv.w;
        }
    }
#pragma unroll
    for (int j = 0; j < 4; ++j)
        out[(size_t)n * M_P + t + 256 * j] = 2.0f * acc[j] - pp[j];
}

// ---------------------------------------------------------------------------
// In-place row softmax, wave-per-row (no LDS/barriers). ~24 us measured.
// ---------------------------------------------------------------------------
__global__ __launch_bounds__(256) void softmax_kernel(float* __restrict__ out) {
    const int lane = threadIdx.x & 63;
    int n = blockIdx.x * 4 + (threadIdx.x >> 6);
    for (int it = 0; it < 2; ++it, n += 8192) {
        float* row = out + (size_t)n * M_P;
        floatx4 v[4];
#pragma unroll
        for (int k = 0; k < 4; ++k)
            v[k] = *((const floatx4*)row + k * 64 + lane);
        float mx = fmaxf(fmaxf(v[0].x, v[0].y), fmaxf(v[0].z, v[0].w));
#pragma unroll
        for (int k = 1; k < 4; ++k)
            mx = fmaxf(mx, fmaxf(fmaxf(v[k].x, v[k].y), fmaxf(v[k].z, v[k].w)));
#pragma unroll
        for (int off = 1; off < 64; off <<= 1) mx = fmaxf(mx, __shfl_xor(mx, off));
        float s = 0.0f;
#pragma unroll
        for (int k = 0; k < 4; ++k) {
            v[k].x = __expf(v[k].x - mx);
            v[k].y = __expf(v[k].y - mx);
            v[k].z = __expf(v[k].z - mx);
            v[k].w = __expf(v[k].w - mx);
            s += v[k].x + v[k].y + v[k].z + v[k].w;
        }
#pragma unroll
        for (int off = 1; off < 64; off <<= 1) s += __shfl_xor(s, off);
        const float inv = 1.0f / s;
#pragma unroll
        for (int k = 0; k < 4; ++k) {
            floatx4 o;
            o.x = v[k].x * inv; o.y = v[k].y * inv;
            o.z = v[k].z * inv; o.w = v[k].w * inv;
            __builtin_nontemporal_store(o, (floatx4*)row + k * 64 + lane);
        }
    }
}

extern "C" void kernel_launch(void* const* d_in, const int* in_sizes, int n_in,
                              void* d_out, int out_size, void* d_ws, size_t ws_size,
                              hipStream_t stream) {
    const float* query = (const float*)d_in[0];
    const float* proto = (const float*)d_in[1];
    float* out = (float*)d_out;

    const size_t pElems = (size_t)M_P * D_K;   // 1M
    const size_t needed = pElems * 2 * 2 + M_P * 4;  // ~4.2 MiB

    if (ws_size >= needed) {
        unsigned short* ph = (unsigned short*)d_ws;
        unsigned short* pl = ph + pElems;
        float* p2 = (float*)(pl + pElems);

        convert_proto_kernel<<<M_P, 256, 0, stream>>>(proto, ph, pl, p2);
        gemm_logits_kernel<<<(N_Q / 256) * (M_P / 256), 512, 0, stream>>>(
            query, ph, pl, p2, out);
    } else {
        naive_logits_kernel<<<N_Q, 256, 0, stream>>>(query, proto, out);
    }
    softmax_kernel<<<2048, 256, 0, stream>>>(out);
}

// Round 5
// 196.709 us; speedup vs baseline: 1.2729x; 1.0073x over previous
//
#include <hip/hip_runtime.h>
#include <stdint.h>

#define N_Q 16384
#define M_P 1024
#define D_K 1024

typedef __attribute__((ext_vector_type(8))) __bf16 bf16x8;
typedef __attribute__((ext_vector_type(4))) float floatx4;
typedef __attribute__((ext_vector_type(4))) unsigned int uint4v;

#define AS1 __attribute__((address_space(1)))
#define AS3 __attribute__((address_space(3)))

__device__ __forceinline__ unsigned short f2bf(float f) {
    unsigned int u = __float_as_uint(f);
    u += 0x7fffu + ((u >> 16) & 1u);   // round-to-nearest-even
    return (unsigned short)(u >> 16);
}
__device__ __forceinline__ float bf2f(unsigned short h) {
    return __uint_as_float(((unsigned int)h) << 16);
}

// Split 8 fp32 (one k-chunk) -> packed bf16 hi (16B) + lo (16B).
__device__ __forceinline__ void split_chunk(floatx4 f0, floatx4 f1,
                                            uint4v* hi, uint4v* lo) {
    float e[8] = {f0.x, f0.y, f0.z, f0.w, f1.x, f1.y, f1.z, f1.w};
    unsigned int hb[4], lb[4];
#pragma unroll
    for (int p = 0; p < 4; ++p) {
        unsigned int u0 = __float_as_uint(e[2 * p]);
        unsigned int u1 = __float_as_uint(e[2 * p + 1]);
        hb[p] = __builtin_amdgcn_perm(u1, u0, 0x07060302);  // [u0>>16, u1>>16]
        float l0 = e[2 * p]     - __uint_as_float(u0 & 0xffff0000u);
        float l1 = e[2 * p + 1] - __uint_as_float(u1 & 0xffff0000u);
        lb[p] = __builtin_amdgcn_perm(__float_as_uint(l1), __float_as_uint(l0),
                                      0x07060302);
    }
    uint4v h = {hb[0], hb[1], hb[2], hb[3]};
    uint4v l = {lb[0], lb[1], lb[2], lb[3]};
    *hi = h;
    *lo = l;
}

// ---------------------------------------------------------------------------
// Proto convert: split fp32 -> bf16 hi/lo + p2[m]. One block per row. ~5 us.
// ---------------------------------------------------------------------------
__global__ __launch_bounds__(256) void convert_proto_kernel(
    const float* __restrict__ proto, unsigned short* __restrict__ ph,
    unsigned short* __restrict__ pl, float* __restrict__ p2) {
    __shared__ float sred[4];
    int m = blockIdx.x;
    int t = threadIdx.x;
    size_t base4 = (size_t)m * (D_K / 4) + t;
    float4 v = ((const float4*)proto)[base4];
    ushort4 h, l;
    h.x = f2bf(v.x); l.x = f2bf(v.x - bf2f(h.x));
    h.y = f2bf(v.y); l.y = f2bf(v.y - bf2f(h.y));
    h.z = f2bf(v.z); l.z = f2bf(v.z - bf2f(h.z));
    h.w = f2bf(v.w); l.w = f2bf(v.w - bf2f(h.w));
    ((ushort4*)ph)[base4] = h;
    ((ushort4*)pl)[base4] = l;
    float sq = v.x * v.x + v.y * v.y + v.z * v.z + v.w * v.w;
#pragma unroll
    for (int off = 1; off < 64; off <<= 1) sq += __shfl_xor(sq, off);
    if ((t & 63) == 0) sred[t >> 6] = sq;
    __syncthreads();
    if (t == 0) p2[m] = sred[0] + sred[1] + sred[2] + sred[3];
}

// ---------------------------------------------------------------------------
// GEMM: logits[n,m] = 2*sum_d q[n,d]*p[m,d] - p2[m], bf16 hi/lo 3-term.
//
// R14: R13 + T4 applied COMPLETELY (zero exposed drains in the main loop).
// R13 post-mortem (95.6us, MfmaUtil 45.5): honest step math = 7170 cyc/step;
// no pipe saturated (LDS-service floor ~2300, MFMA 931/SIMD, VALU ~1400) ->
// latency-bound, 8 lockstep waves, 1 block/CU structural (acc=128 VGPR).
// lgkm read-ahead already at hw cap (16 outstanding vs lgkmcnt max 15).
// Remaining exposed drains, now removed:
//  * B was issued 1 step ahead, waited vmcnt(4) at step end (~1000cy cover
//    vs ~900cy HBM-miss: marginal). Now B TRIPLE-buffered (LDS 128->160KB,
//    still 1 block/CU, m243 precedent): B(t+2) issued at step t -> ~2 steps
//    (~4000cy) in flight; end-of-step wait = counted vmcnt(8) (keeps
//    B(t+2)+A(t+2) in flight). vmcnt(0) only at t=30.
//  * pre-mfma2(6) lgkmcnt(0) drained the 4 A ds_writes that nothing reads
//    until after the barrier. Now counted lgkm(4) before mfma2(6) (A67
//    reads done, writes outstanding); write-drain lgkm(0) AFTER the final
//    MFMA cluster (overlaps it), then vmcnt(8), then the one barrier.
// Loop unrolled x6 (lcm of A%2,B%3) -> all buffer indices literal (rule 20).
// Swizzles/numerics/MFMA order bit-identical to R7/R13.
// ---------------------------------------------------------------------------
__global__ __launch_bounds__(512, 2) void gemm_logits_kernel(
    const float* __restrict__ query,
    const unsigned short* __restrict__ ph, const unsigned short* __restrict__ pl,
    const float* __restrict__ p2, float* __restrict__ out) {
    __shared__ unsigned short sAh[2][16 * 512];   // 2 x 16 KB
    __shared__ unsigned short sAl[2][16 * 512];   // 2 x 16 KB
    __shared__ unsigned short sBh[3][16 * 512];   // 3 x 16 KB
    __shared__ unsigned short sBl[3][16 * 512];   // 3 x 16 KB  (160 KB)

    const int tid = threadIdx.x;
    const int wave = tid >> 6;   // 0..7
    const int lane = tid & 63;
    const int wr = wave >> 2;    // 0..1: row half (128 rows)
    const int wc = wave & 3;     // 0..3: col quarter (64 cols)

    // XCD-aware: 8 chunks of 32 blocks; chunk = same col-tile, 32 row-tiles.
    const int b = blockIdx.x;            // 0..255
    const int v = (b & 7) * 32 + (b >> 3);
    const int colt = v >> 6;             // 0..3
    const int rowt = v & 63;             // 0..63
    const int row0 = rowt * 256;
    const int col0 = colt * 256;

    // B staging (R4-verified pre-swizzled source, linear gload_lds dest):
    const int rlB = lane >> 2;
    const int cioB = (lane & 3) ^ ((lane >> 3) & 3);
    const int halfB = wave >> 2;         // 0: hi, 1: lo
    const int sgB = wave & 3;
    const unsigned short* gB = (halfB ? pl : ph)
        + (size_t)(col0 + sgB * 64 + rlB) * D_K + cioB * 8;

    // A staging: wave covers rows wave*32..wave*32+31 (2 subtiles of 16).
    const int rlA = lane >> 2;          // 0..15
    const int cA = lane & 3;            // k-granule 0..3
    const AS1 float* gA = (const AS1 float*)query
        + (size_t)(row0 + wave * 32 + rlA) * D_K + cA * 8;
    const int wroff = (4 * rlA + (cA ^ ((rlA >> 1) & 3))) * 8;  // shorts

    // fragment read offsets (swizzle-matched, conflict-free, R4-verified)
    const int rsel = lane & 15;
    const int kq = lane >> 4;
    const int fragoff = (4 * rsel + (kq ^ ((rsel >> 1) & 3))) * 8;

    floatx4 zero = {0.0f, 0.0f, 0.0f, 0.0f};
    floatx4 acc[8][4];
#pragma unroll
    for (int i = 0; i < 8; ++i)
#pragma unroll
        for (int j = 0; j < 4; ++j) acc[i][j] = zero;

    floatx4 f0[2], f1[2];        // A prefetch regs (16 VGPR)
    bf16x8 bh[4], bl[4];         // B fragments (held one K-step)
    bf16x8 ah[2][2], al[2][2];   // A fragments, 2 reg-sets (read-ahead)

    auto issueA = [&](int kb) {
#pragma unroll
        for (int s = 0; s < 2; ++s) {
            const AS1 float* p = gA + (size_t)(s * 16) * D_K + kb;
            f0[s] = *(const AS1 floatx4*)p;
            f1[s] = *(const AS1 floatx4*)(p + 4);
        }
    };
    auto issueB = [&](int kb, int dst) {
        unsigned short* dstB = (halfB ? sBl[dst] : sBh[dst]) + sgB * 4 * 512;
#pragma unroll
        for (int s = 0; s < 4; ++s)
            __builtin_amdgcn_global_load_lds(
                (const AS1 unsigned int*)(const void*)(gB + (size_t)(s * 16) * D_K + kb),
                (AS3 unsigned int*)(void*)(dstB + s * 512), 16, 0, 0);
    };
    auto writeA = [&](int nxt, int s) {
        uint4v hi, lo;
        split_chunk(f0[s], f1[s], &hi, &lo);
        const int off = (wave * 2 + s) * 512 + wroff;
        *(uint4v*)(sAh[nxt] + off) = hi;
        *(uint4v*)(sAl[nxt] + off) = lo;
    };
    auto ldBfrag = [&](int curB) {
#pragma unroll
        for (int j = 0; j < 4; ++j) {
            const int boff = (wc * 4 + j) * 512 + fragoff;
            bh[j] = *(const bf16x8*)(sBh[curB] + boff);
            bl[j] = *(const bf16x8*)(sBl[curB] + boff);
        }
    };
    // load A-frag pair (i0, i0+1) into reg-set `set` (literal at all sites)
    auto ldA = [&](int cur, int i0, int set) {
#pragma unroll
        for (int t = 0; t < 2; ++t) {
            const int aoff = (wr * 8 + i0 + t) * 512 + fragoff;
            ah[set][t] = *(const bf16x8*)(sAh[cur] + aoff);
            al[set][t] = *(const bf16x8*)(sAl[cur] + aoff);
        }
    };
    auto mfma2 = [&](int i0, int set) {
#pragma unroll
        for (int j = 0; j < 4; ++j)
#pragma unroll
            for (int t = 0; t < 2; ++t) {
                acc[i0 + t][j] = __builtin_amdgcn_mfma_f32_16x16x32_bf16(ah[set][t], bh[j], acc[i0 + t][j], 0, 0, 0);
                acc[i0 + t][j] = __builtin_amdgcn_mfma_f32_16x16x32_bf16(ah[set][t], bl[j], acc[i0 + t][j], 0, 0, 0);
                acc[i0 + t][j] = __builtin_amdgcn_mfma_f32_16x16x32_bf16(al[set][t], bh[j], acc[i0 + t][j], 0, 0, 0);
            }
    };

#define LGKM_MFMA(n, i0, set)                                   \
    asm volatile("s_waitcnt lgkmcnt(" #n ")" ::: "memory");     \
    __builtin_amdgcn_sched_barrier(0);                          \
    __builtin_amdgcn_s_setprio(1);                              \
    mfma2(i0, set);                                             \
    __builtin_amdgcn_s_setprio(0);

    // One K-step t. DS order: [B 8r][A01 4r][A23 4r] |4| [A45 4r] |4|
    // [A67 4r] |4| [W 4w] ... lgkm(4) pre-mfma2(6) (A67 done, writes out),
    // lgkm(0) AFTER mfma2(6). Vmem order: [B(t+2) x4][A(t+2) x4];
    // end-of-step vmcnt(8) = B(t+1) (issued last step) landed. Never 0
    // until t=30.
    auto stepf = [&](int kb2, int curA, int nxtA, int curB, int dstB,
                     bool pfB2, bool pfA2, bool pfW) {
        if (pfB2) issueB(kb2, dstB);
        ldBfrag(curB);               // 8 reads
        ldA(curA, 0, 0);             // 4 reads
        ldA(curA, 2, 1);             // 4 reads   [16 outstanding, hw-capped]
        LGKM_MFMA(4, 0, 0)           // B+A01 done; A23 in flight under MFMA
        ldA(curA, 4, 0);
        LGKM_MFMA(4, 2, 1)           // A23 done; A45 in flight under MFMA
        ldA(curA, 6, 1);
        LGKM_MFMA(4, 4, 0)           // A45 done; A67 in flight under MFMA
        if (pfW) { writeA(nxtA, 0); writeA(nxtA, 1); }  // VALU + 4 ds_write
        if (pfA2) issueA(kb2);       // f-regs free after split VALU
        if (pfW) { asm volatile("s_waitcnt lgkmcnt(4)" ::: "memory"); }
        else     { asm volatile("s_waitcnt lgkmcnt(0)" ::: "memory"); }
        __builtin_amdgcn_sched_barrier(0);
        __builtin_amdgcn_s_setprio(1);
        mfma2(6, 1);
        __builtin_amdgcn_s_setprio(0);
        asm volatile("s_waitcnt lgkmcnt(0)" ::: "memory");  // ds_writes drained
        if (pfB2)      { asm volatile("s_waitcnt vmcnt(8)" ::: "memory"); }
        else if (pfW)  { asm volatile("s_waitcnt vmcnt(0)" ::: "memory"); }
        __builtin_amdgcn_s_barrier();   // the ONE barrier per step
    };

    // prologue: B(t0)->b0, B(t1)->b1 (2-deep from the start); A(t0) split
    // to bA0; A(t1) regs in flight across the barrier.
    issueB(0, 0);               // 4 vmem (oldest)
    issueB(32, 1);              // 4 vmem
    issueA(0);                  // 4 vmem (compiler waits vmcnt(8) at writeA)
    writeA(0, 0);
    writeA(0, 1);
    issueA(32);                 // A(t1) in flight
    asm volatile("s_waitcnt lgkmcnt(0)" ::: "memory");
    asm volatile("s_waitcnt vmcnt(8)" ::: "memory");   // B(t0) landed
    __builtin_amdgcn_s_barrier();

    // 30 steps, unrolled x6 so curA (t%2) and curB (t%3) are literals.
    for (int kt = 0; kt < 30; kt += 6) {
        const int kb = kt * 32;
        stepf(kb + 2 * 32, 0, 1, 0, 2, true, true, true);   // t=kt+0
        stepf(kb + 3 * 32, 1, 0, 1, 0, true, true, true);   // t=kt+1
        stepf(kb + 4 * 32, 0, 1, 2, 1, true, true, true);   // t=kt+2
        stepf(kb + 5 * 32, 1, 0, 0, 2, true, true, true);   // t=kt+3
        stepf(kb + 6 * 32, 0, 1, 1, 0, true, true, true);   // t=kt+4
        stepf(kb + 7 * 32, 1, 0, 2, 1, true, true, true);   // t=kt+5
    }
    stepf(0, 0, 1, 0, 2, false, false, true);   // t=30: write A(31), drain vm
    stepf(0, 1, 0, 1, 0, false, false, false);  // t=31: compute only

#undef LGKM_MFMA

    // ---- epilogue: logits = 2*qp - p2[col] ----
    // C layout (verified m89/m91): col = lane&15, row = (lane>>4)*4 + reg
#pragma unroll
    for (int j = 0; j < 4; ++j) {
        const int gc = col0 + wc * 64 + j * 16 + rsel;
        const float p2v = p2[gc];
#pragma unroll
        for (int i = 0; i < 8; ++i) {
            const int gr = row0 + wr * 128 + i * 16 + kq * 4;
#pragma unroll
            for (int r = 0; r < 4; ++r) {
                out[(size_t)(gr + r) * M_P + gc] = 2.0f * acc[i][j][r] - p2v;
            }
        }
    }
}

// ---------------------------------------------------------------------------
// Fallback (tiny workspace): naive fp32 logits + separate softmax.
// ---------------------------------------------------------------------------
__global__ __launch_bounds__(256) void naive_logits_kernel(
    const float* __restrict__ query, const float* __restrict__ proto,
    float* __restrict__ out) {
    __shared__ float qs[D_K];
    int n = blockIdx.x;
    int t = threadIdx.x;
    ((float4*)qs)[t] = ((const float4*)(query + (size_t)n * D_K))[t];
    __syncthreads();
    float acc[4] = {0.f, 0.f, 0.f, 0.f};
    float pp[4] = {0.f, 0.f, 0.f, 0.f};
    for (int d = 0; d < D_K; d += 4) {
        float4 qv = *(const float4*)(qs + d);
#pragma unroll
        for (int j = 0; j < 4; ++j) {
            const float4 pv = *(const float4*)(proto + (size_t)(t + 256 * j) * D_K + d);
            acc[j] += qv.x * pv.x + qv.y * pv.y + qv.z * pv.z + qv.w * pv.w;
            pp[j] += pv.x * pv.x + pv.y * pv.y + pv.z * pv.z + pv.w * pv.w;
        }
    }
#pragma unroll
    for (int j = 0; j < 4; ++j)
        out[(size_t)n * M_P + t + 256 * j] = 2.0f * acc[j] - pp[j];
}

// ---------------------------------------------------------------------------
// In-place row softmax, wave-per-row (no LDS/barriers). ~24 us measured.
// ---------------------------------------------------------------------------
__global__ __launch_bounds__(256) void softmax_kernel(float* __restrict__ out) {
    const int lane = threadIdx.x & 63;
    int n = blockIdx.x * 4 + (threadIdx.x >> 6);
    for (int it = 0; it < 2; ++it, n += 8192) {
        float* row = out + (size_t)n * M_P;
        floatx4 v[4];
#pragma unroll
        for (int k = 0; k < 4; ++k)
            v[k] = *((const floatx4*)row + k * 64 + lane);
        float mx = fmaxf(fmaxf(v[0].x, v[0].y), fmaxf(v[0].z, v[0].w));
#pragma unroll
        for (int k = 1; k < 4; ++k)
            mx = fmaxf(mx, fmaxf(fmaxf(v[k].x, v[k].y), fmaxf(v[k].z, v[k].w)));
#pragma unroll
        for (int off = 1; off < 64; off <<= 1) mx = fmaxf(mx, __shfl_xor(mx, off));
        float s = 0.0f;
#pragma unroll
        for (int k = 0; k < 4; ++k) {
            v[k].x = __expf(v[k].x - mx);
            v[k].y = __expf(v[k].y - mx);
            v[k].z = __expf(v[k].z - mx);
            v[k].w = __expf(v[k].w - mx);
            s += v[k].x + v[k].y + v[k].z + v[k].w;
        }
#pragma unroll
        for (int off = 1; off < 64; off <<= 1) s += __shfl_xor(s, off);
        const float inv = 1.0f / s;
#pragma unroll
        for (int k = 0; k < 4; ++k) {
            floatx4 o;
            o.x = v[k].x * inv; o.y = v[k].y * inv;
            o.z = v[k].z * inv; o.w = v[k].w * inv;
            __builtin_nontemporal_store(o, (floatx4*)row + k * 64 + lane);
        }
    }
}

extern "C" void kernel_launch(void* const* d_in, const int* in_sizes, int n_in,
                              void* d_out, int out_size, void* d_ws, size_t ws_size,
                              hipStream_t stream) {
    const float* query = (const float*)d_in[0];
    const float* proto = (const float*)d_in[1];
    float* out = (float*)d_out;

    const size_t pElems = (size_t)M_P * D_K;   // 1M
    const size_t needed = pElems * 2 * 2 + M_P * 4;  // ~4.2 MiB

    if (ws_size >= needed) {
        unsigned short* ph = (unsigned short*)d_ws;
        unsigned short* pl = ph + pElems;
        float* p2 = (float*)(pl + pElems);

        convert_proto_kernel<<<M_P, 256, 0, stream>>>(proto, ph, pl, p2);
        gemm_logits_kernel<<<(N_Q / 256) * (M_P / 256), 512, 0, stream>>>(
            query, ph, pl, p2, out);
    } else {
        naive_logits_kernel<<<N_Q, 256, 0, stream>>>(query, proto, out);
    }
    softmax_kernel<<<2048, 256, 0, stream>>>(out);
}